// Round 1
// baseline (182.802 us; speedup 1.0000x reference)
//
#include <hip/hip_runtime.h>
#include <cstdint>

#define SEQ 4096
#define NH 8
#define DH 32

typedef __bf16 bf16x8 __attribute__((ext_vector_type(8)));
typedef float f32x4 __attribute__((ext_vector_type(4)));
typedef float f32x8 __attribute__((ext_vector_type(8)));
typedef unsigned short u16x8 __attribute__((ext_vector_type(8)));

__device__ inline unsigned short f2bf(float f) {
    unsigned u = __builtin_bit_cast(unsigned, f);
    u += 0x7fffu + ((u >> 16) & 1u);
    return (unsigned short)(u >> 16);
}

__device__ inline bf16x8 cvt_f8(f32x8 v) {
    u16x8 r;
#pragma unroll
    for (int i = 0; i < 8; i++) r[i] = f2bf(v[i]);
    return __builtin_bit_cast(bf16x8, r);
}

__device__ inline bf16x8 ld_bf8(const unsigned short* p) {
    return __builtin_bit_cast(bf16x8, *(const u16x8*)p);
}

// ---------------- Kernel 1: QKV projections ----------------
// y = X @ W^T  (M=4096, N=256, K=256), per-wave 16x16 tile.
// sel 0: Q[h][m][d] *= (1/sqrt(32))*log2(e)   (folded so attn uses exp2 directly)
// sel 1: K[h][n][d]
// sel 2: Vt[h][d][n] *= radial[n]             (transposed for PV B-operand)
__global__ __launch_bounds__(256) void proj_kernel(
    const float* __restrict__ X0, const float* __restrict__ X1, const float* __restrict__ X2,
    const float* __restrict__ W0, const float* __restrict__ W1, const float* __restrict__ W2,
    const float* __restrict__ radial,
    unsigned short* __restrict__ outq, unsigned short* __restrict__ outk,
    unsigned short* __restrict__ outv) {
    const int sel = blockIdx.y;
    const float* X = (sel == 0) ? X0 : (sel == 1) ? X1 : X2;
    const float* W = (sel == 0) ? W0 : (sel == 1) ? W1 : W2;
    const int lane = threadIdx.x & 63;
    const int w = threadIdx.x >> 6;
    const int cl = lane & 15;
    const int hi = lane >> 4;
    const int t = blockIdx.x * 4 + w;
    const int m0 = (t >> 4) * 16;
    const int n0 = (t & 15) * 16;

    const f32x8* xp = (const f32x8*)(X + (m0 + cl) * 256 + hi * 8);
    const f32x8* wp = (const f32x8*)(W + (n0 + cl) * 256 + hi * 8);

    f32x4 acc = {0.f, 0.f, 0.f, 0.f};
#pragma unroll
    for (int ks = 0; ks < 8; ks++) {
        bf16x8 a = cvt_f8(xp[ks * 4]);  // stride 32 floats = 4 * f32x8
        bf16x8 b = cvt_f8(wp[ks * 4]);
        acc = __builtin_amdgcn_mfma_f32_16x16x32_bf16(a, b, acc, 0, 0, 0);
    }

    const int cn = n0 + cl;       // output feature
    const int h = cn >> 5;
    const int d = cn & 31;
    const float QSCALE = 0.17677669529663689f * 1.4426950408889634f;
#pragma unroll
    for (int r = 0; r < 4; r++) {
        const int cm = m0 + hi * 4 + r;  // seq position
        float v = acc[r];
        if (sel == 0) {
            outq[(h * SEQ + cm) * DH + d] = f2bf(v * QSCALE);
        } else if (sel == 1) {
            outk[(h * SEQ + cm) * DH + d] = f2bf(v);
        } else {
            outv[(h * DH + d) * SEQ + cm] = f2bf(v * radial[cm]);
        }
    }
}

// ---------------- Kernel 2: flash attention ----------------
// 1 wave = 16 q-rows of one head. Iterate 64-key blocks:
//   4x QK mfma (K=32=D in one step) -> exp2 -> P to swizzled LDS -> 4x PV mfma.
// No max-subtraction (logits bounded, f32-safe); denominator reduced once at end.
__global__ __launch_bounds__(256) void attn_kernel(
    const unsigned short* __restrict__ Q, const unsigned short* __restrict__ K,
    const unsigned short* __restrict__ Vt, unsigned short* __restrict__ An) {
    __shared__ __align__(16) unsigned short P[4][16][64];
    const int lane = threadIdx.x & 63;
    const int w = threadIdx.x >> 6;
    const int cl = lane & 15;
    const int hi = lane >> 4;
    const int wt = blockIdx.x * 4 + w;
    const int head = wt >> 8;
    const int m0 = (wt & 255) * 16;

    const unsigned short* qh = Q + head * (SEQ * DH);
    const unsigned short* kh = K + head * (SEQ * DH);
    const unsigned short* vh = Vt + head * (DH * SEQ);

    const bf16x8 qa = ld_bf8(qh + (m0 + cl) * DH + hi * 8);

    unsigned short(*pl)[64] = P[w];
    f32x4 acc0 = {0.f, 0.f, 0.f, 0.f};
    f32x4 acc1 = {0.f, 0.f, 0.f, 0.f};
    float ls[4] = {0.f, 0.f, 0.f, 0.f};

    const int rdswz = (cl & 7) << 3;  // read-side XOR swizzle (row = cl)

    for (int nb = 0; nb < 64; nb++) {
        const int n0 = nb * 64;
        f32x4 sc[4];
#pragma unroll
        for (int jb = 0; jb < 4; jb++) {
            bf16x8 kb = ld_bf8(kh + (n0 + jb * 16 + cl) * DH + hi * 8);
            f32x4 z = {0.f, 0.f, 0.f, 0.f};
            sc[jb] = __builtin_amdgcn_mfma_f32_16x16x32_bf16(qa, kb, z, 0, 0, 0);
        }
#pragma unroll
        for (int jb = 0; jb < 4; jb++) {
#pragma unroll
            for (int r = 0; r < 4; r++) {
                float p = exp2f(sc[jb][r]);  // log2e pre-folded into Q
                ls[r] += p;
                const int rr = hi * 4 + r;
                pl[rr][(jb * 16 + cl) ^ ((rr & 7) << 3)] = f2bf(p);
            }
        }
        asm volatile("s_waitcnt lgkmcnt(0)" ::: "memory");
#pragma unroll
        for (int nc = 0; nc < 2; nc++) {
            bf16x8 pa = ld_bf8(&pl[cl][(nc * 32 + hi * 8) ^ rdswz]);
            bf16x8 vb0 = ld_bf8(vh + (cl)*SEQ + n0 + nc * 32 + hi * 8);
            acc0 = __builtin_amdgcn_mfma_f32_16x16x32_bf16(pa, vb0, acc0, 0, 0, 0);
            bf16x8 vb1 = ld_bf8(vh + (16 + cl) * SEQ + n0 + nc * 32 + hi * 8);
            acc1 = __builtin_amdgcn_mfma_f32_16x16x32_bf16(pa, vb1, acc1, 0, 0, 0);
        }
        asm volatile("" ::: "memory");  // keep next iter's P writes after these reads
    }

#pragma unroll
    for (int r = 0; r < 4; r++) {
        float t = ls[r];
        t += __shfl_xor(t, 1);
        t += __shfl_xor(t, 2);
        t += __shfl_xor(t, 4);
        t += __shfl_xor(t, 8);
        const float inv = 1.0f / t;
        const int m = m0 + hi * 4 + r;
        An[m * 256 + head * DH + cl] = f2bf(acc0[r] * inv);
        An[m * 256 + head * DH + 16 + cl] = f2bf(acc1[r] * inv);
    }
}

// ---------------- Kernel 3: output projection ----------------
// out = attn(bf16) @ Wo^T, fp32 out.
__global__ __launch_bounds__(256) void oproj_kernel(
    const unsigned short* __restrict__ An, const float* __restrict__ Wo,
    float* __restrict__ out) {
    const int lane = threadIdx.x & 63;
    const int w = threadIdx.x >> 6;
    const int cl = lane & 15;
    const int hi = lane >> 4;
    const int t = blockIdx.x * 4 + w;
    const int m0 = (t >> 4) * 16;
    const int n0 = (t & 15) * 16;

    const unsigned short* ap = An + (m0 + cl) * 256 + hi * 8;
    const f32x8* wp = (const f32x8*)(Wo + (n0 + cl) * 256 + hi * 8);

    f32x4 acc = {0.f, 0.f, 0.f, 0.f};
#pragma unroll
    for (int ks = 0; ks < 8; ks++) {
        bf16x8 a = ld_bf8(ap + ks * 32);
        bf16x8 b = cvt_f8(wp[ks * 4]);
        acc = __builtin_amdgcn_mfma_f32_16x16x32_bf16(a, b, acc, 0, 0, 0);
    }
#pragma unroll
    for (int r = 0; r < 4; r++) {
        out[(m0 + hi * 4 + r) * 256 + n0 + cl] = acc[r];
    }
}

extern "C" void kernel_launch(void* const* d_in, const int* in_sizes, int n_in,
                              void* d_out, int out_size, void* d_ws, size_t ws_size,
                              hipStream_t stream) {
    const float* query = (const float*)d_in[0];
    const float* key_ = (const float*)d_in[1];
    const float* value = (const float*)d_in[2];
    const float* radial = (const float*)d_in[3];
    const float* Wq = (const float*)d_in[4];
    const float* Wk = (const float*)d_in[5];
    const float* Wv = (const float*)d_in[6];
    const float* Wo = (const float*)d_in[7];

    unsigned short* wq = (unsigned short*)d_ws;            // Q[h][m][d]  2MB
    unsigned short* wk = wq + SEQ * 256;                   // K[h][n][d]  2MB
    unsigned short* wv = wk + SEQ * 256;                   // Vt[h][d][n] 2MB
    unsigned short* wa = wv + SEQ * 256;                   // attn bf16   2MB

    proj_kernel<<<dim3(1024, 3), 256, 0, stream>>>(query, key_, value, Wq, Wk, Wv,
                                                   radial, wq, wk, wv);
    attn_kernel<<<512, 256, 0, stream>>>(wq, wk, wv, wa);
    oproj_kernel<<<1024, 256, 0, stream>>>(wa, Wo, (float*)d_out);
}

// Round 2
// 99.685 us; speedup vs baseline: 1.8338x; 1.8338x over previous
//
#include <hip/hip_runtime.h>
#include <cstdint>

#define SEQ 4096
#define NH 8
#define DH 32

typedef __bf16 bf16x8 __attribute__((ext_vector_type(8)));
typedef float f32x4 __attribute__((ext_vector_type(4)));
typedef float f32x8 __attribute__((ext_vector_type(8)));
typedef float f32x16 __attribute__((ext_vector_type(16)));
typedef unsigned short u16x8 __attribute__((ext_vector_type(8)));
typedef unsigned u32x4 __attribute__((ext_vector_type(4)));
typedef unsigned u32x2 __attribute__((ext_vector_type(2)));
typedef int i32x2 __attribute__((ext_vector_type(2)));

#define MFMA16 __builtin_amdgcn_mfma_f32_16x16x32_bf16
#define MFMA32 __builtin_amdgcn_mfma_f32_32x32x16_bf16

__device__ inline bf16x8 ld_bf8(const unsigned short* p) {
    return __builtin_bit_cast(bf16x8, *(const u16x8*)p);
}
__device__ inline unsigned short bfbits(float v) {
    return __builtin_bit_cast(unsigned short, (__bf16)v);
}
__device__ inline bf16x8 cvt_f8(f32x8 v) {
    bf16x8 r;
#pragma unroll
    for (int i = 0; i < 8; i++) r[i] = (__bf16)v[i];
    return r;
}
__device__ inline unsigned cvtpk(float lo, float hi) {
    unsigned r;
    asm("v_cvt_pk_bf16_f32 %0, %1, %2" : "=v"(r) : "v"(lo), "v"(hi));
    return r;
}

// ---------------- Kernel 1: QKV projections (32x32 tile / wave) ----------------
// sel 0: Q[h][m][d] *= (1/sqrt(32))*log2(e)
// sel 1: K[h][n][d]
// sel 2: Vt[h][d][n] *= radial[n]
__global__ __launch_bounds__(256) void proj_kernel(
    const float* __restrict__ X0, const float* __restrict__ X1, const float* __restrict__ X2,
    const float* __restrict__ W0, const float* __restrict__ W1, const float* __restrict__ W2,
    const float* __restrict__ radial,
    unsigned short* __restrict__ outq, unsigned short* __restrict__ outk,
    unsigned short* __restrict__ outv) {
    const int sel = blockIdx.y;
    const float* X = (sel == 0) ? X0 : (sel == 1) ? X1 : X2;
    const float* W = (sel == 0) ? W0 : (sel == 1) ? W1 : W2;
    const int lane = threadIdx.x & 63;
    const int w = threadIdx.x >> 6;
    const int cl = lane & 15;
    const int h4 = lane >> 4;
    const int t = blockIdx.x * 4 + w;      // 1024 tiles: 128 x 8
    const int m0 = (t >> 3) * 32;
    const int n0 = (t & 7) * 32;

    const float* xa0 = X + (m0 + cl) * 256 + h4 * 8;
    const float* xa1 = xa0 + 16 * 256;
    const float* wb0 = W + (n0 + cl) * 256 + h4 * 8;
    const float* wb1 = wb0 + 16 * 256;

    f32x4 acc00 = {0.f, 0.f, 0.f, 0.f}, acc01 = {0.f, 0.f, 0.f, 0.f};
    f32x4 acc10 = {0.f, 0.f, 0.f, 0.f}, acc11 = {0.f, 0.f, 0.f, 0.f};
#pragma unroll
    for (int ksi = 0; ksi < 8; ksi++) {
        bf16x8 a0 = cvt_f8(*(const f32x8*)(xa0 + ksi * 32));
        bf16x8 a1 = cvt_f8(*(const f32x8*)(xa1 + ksi * 32));
        bf16x8 b0 = cvt_f8(*(const f32x8*)(wb0 + ksi * 32));
        bf16x8 b1 = cvt_f8(*(const f32x8*)(wb1 + ksi * 32));
        acc00 = MFMA16(a0, b0, acc00, 0, 0, 0);
        acc01 = MFMA16(a0, b1, acc01, 0, 0, 0);
        acc10 = MFMA16(a1, b0, acc10, 0, 0, 0);
        acc11 = MFMA16(a1, b1, acc11, 0, 0, 0);
    }

    const float QSCALE = 0.17677669529663689f * 1.4426950408889634f;
#pragma unroll
    for (int am = 0; am < 2; am++) {
#pragma unroll
        for (int r = 0; r < 4; r++) {
            const int cm = m0 + am * 16 + h4 * 4 + r;
            float rm = (sel == 2) ? radial[cm] : 0.f;
#pragma unroll
            for (int bn = 0; bn < 2; bn++) {
                float v = am ? (bn ? acc11[r] : acc10[r]) : (bn ? acc01[r] : acc00[r]);
                const int cn = n0 + bn * 16 + cl;
                const int h = cn >> 5, d = cn & 31;
                if (sel == 0) outq[(h * SEQ + cm) * DH + d] = bfbits(v * QSCALE);
                else if (sel == 1) outk[(h * SEQ + cm) * DH + d] = bfbits(v);
                else outv[(h * DH + d) * SEQ + cm] = bfbits(v * rm);
            }
        }
    }
}

// ---------------- Kernel 2: flash attention, swapped operands ----------------
// Wave = 32 q-rows, KSPLIT=2 over keys. S^T = mfma32(K,Q): lane holds 16 scores
// of q-row (lane&31). P->bf16 via cvt_pk + permlane32_swap (no LDS in loop).
// O^T = mfma32(Vt,P): lane holds 16 d's of q-row (lane&31); denom is lane-local.
__global__ __launch_bounds__(256) void attn_kernel(
    const unsigned short* __restrict__ Q, const unsigned short* __restrict__ K,
    const unsigned short* __restrict__ Vt, unsigned short* __restrict__ An) {
    __shared__ float cO[2][64][17];
    __shared__ float cls[2][64];
    const int lane = threadIdx.x & 63;
    const int w = threadIdx.x >> 6;
    const int l31 = lane & 31;
    const int hi = lane >> 5;

    // XCD-chunked remap: 512 blocks head-major -> each XCD owns one head
    int bid = blockIdx.x;
    bid = (bid & 7) * 64 + (bid >> 3);
    const int head = bid >> 6;
    const int blk = bid & 63;
    const int pair = w >> 1;         // waves (0,1) and (2,3) share a q-tile
    const int qt = blk * 2 + pair;
    const int ks = w & 1;
    const int m0 = qt * 32;

    const unsigned short* qh = Q + head * (SEQ * DH);
    const unsigned short* kh = K + head * (SEQ * DH);
    const unsigned short* vh = Vt + head * (DH * SEQ);

    const bf16x8 qf0 = ld_bf8(qh + (m0 + l31) * DH + hi * 8);        // d in [0,16)
    const bf16x8 qf1 = ld_bf8(qh + (m0 + l31) * DH + 16 + hi * 8);   // d in [16,32)

    f32x16 oacc = {0.f, 0.f, 0.f, 0.f, 0.f, 0.f, 0.f, 0.f,
                   0.f, 0.f, 0.f, 0.f, 0.f, 0.f, 0.f, 0.f};
    float ls = 0.f;

    const unsigned short* kp = kh + (ks * 2048 + l31) * DH + hi * 8;
    const unsigned short* vp = vh + l31 * SEQ + ks * 2048 + hi * 8;

    for (int nb = 0; nb < 64; nb++) {
        bf16x8 kf0 = ld_bf8(kp);
        bf16x8 kf1 = ld_bf8(kp + 16);
        f32x16 s = {0.f, 0.f, 0.f, 0.f, 0.f, 0.f, 0.f, 0.f,
                    0.f, 0.f, 0.f, 0.f, 0.f, 0.f, 0.f, 0.f};
        s = MFMA32(kf0, qf0, s, 0, 0, 0);
        s = MFMA32(kf1, qf1, s, 0, 0, 0);
        // lane holds P[q=l31][key = n0 + (reg&3)+8*(reg>>2)+4*hi]
        float p[16];
#pragma unroll
        for (int r = 0; r < 16; r++) p[r] = exp2f(s[r]);
        {   // tree-sum for short dependency chain
            float s01 = p[0] + p[1], s23 = p[2] + p[3], s45 = p[4] + p[5], s67 = p[6] + p[7];
            float s89 = p[8] + p[9], sab = p[10] + p[11], scd = p[12] + p[13], sef = p[14] + p[15];
            ls += ((s01 + s23) + (s45 + s67)) + ((s89 + sab) + (scd + sef));
        }
        // Repack P into the B-operand fragment (col=q, k=key) for the two PV MFMAs.
        unsigned a01 = cvtpk(p[0], p[1]), a23 = cvtpk(p[2], p[3]);
        unsigned a45 = cvtpk(p[4], p[5]), a67 = cvtpk(p[6], p[7]);
        i32x2 r0 = __builtin_amdgcn_permlane32_swap((int)a01, (int)a45, false, false);
        i32x2 r1 = __builtin_amdgcn_permlane32_swap((int)a23, (int)a67, false, false);
        u32x4 pb0w = {(unsigned)r0[0], (unsigned)r1[0], (unsigned)r0[1], (unsigned)r1[1]};
        unsigned a89 = cvtpk(p[8], p[9]), aab = cvtpk(p[10], p[11]);
        unsigned acd = cvtpk(p[12], p[13]), aef = cvtpk(p[14], p[15]);
        i32x2 r2 = __builtin_amdgcn_permlane32_swap((int)a89, (int)acd, false, false);
        i32x2 r3 = __builtin_amdgcn_permlane32_swap((int)aab, (int)aef, false, false);
        u32x4 pb1w = {(unsigned)r2[0], (unsigned)r3[0], (unsigned)r2[1], (unsigned)r3[1]};

        bf16x8 vt0 = ld_bf8(vp);         // keys [n0, n0+16)
        bf16x8 vt1 = ld_bf8(vp + 16);    // keys [n0+16, n0+32)
        oacc = MFMA32(vt0, __builtin_bit_cast(bf16x8, pb0w), oacc, 0, 0, 0);
        oacc = MFMA32(vt1, __builtin_bit_cast(bf16x8, pb1w), oacc, 0, 0, 0);
        kp += 32 * DH;
        vp += 32;
    }

    ls += __shfl_xor(ls, 32);
    if (ks == 1) {
#pragma unroll
        for (int i = 0; i < 16; i++) cO[pair][lane][i] = oacc[i];
        if (hi == 0) cls[pair][l31] = ls;
    }
    __syncthreads();
    if (ks == 0) {
#pragma unroll
        for (int i = 0; i < 16; i++) oacc[i] += cO[pair][lane][i];
        ls += cls[pair][l31];
        const float inv = 1.0f / ls;
        unsigned short* op = An + (m0 + l31) * 256 + head * DH;
#pragma unroll
        for (int g = 0; g < 4; g++) {
            // regs 4g..4g+3 -> d = 8g + 4*hi + (0..3), consecutive
            unsigned lo = cvtpk(oacc[4 * g] * inv, oacc[4 * g + 1] * inv);
            unsigned hw = cvtpk(oacc[4 * g + 2] * inv, oacc[4 * g + 3] * inv);
            *(u32x2*)(op + 8 * g + 4 * hi) = (u32x2){lo, hw};
        }
    }
}

// ---------------- Kernel 3: output projection (32x32 tile / wave) ----------------
__global__ __launch_bounds__(256) void oproj_kernel(
    const unsigned short* __restrict__ An, const float* __restrict__ Wo,
    float* __restrict__ out) {
    const int lane = threadIdx.x & 63;
    const int w = threadIdx.x >> 6;
    const int cl = lane & 15;
    const int h4 = lane >> 4;
    const int t = blockIdx.x * 4 + w;
    const int m0 = (t >> 3) * 32;
    const int n0 = (t & 7) * 32;

    const unsigned short* ap0 = An + (m0 + cl) * 256 + h4 * 8;
    const unsigned short* ap1 = ap0 + 16 * 256;
    const float* wb0 = Wo + (n0 + cl) * 256 + h4 * 8;
    const float* wb1 = wb0 + 16 * 256;

    f32x4 acc00 = {0.f, 0.f, 0.f, 0.f}, acc01 = {0.f, 0.f, 0.f, 0.f};
    f32x4 acc10 = {0.f, 0.f, 0.f, 0.f}, acc11 = {0.f, 0.f, 0.f, 0.f};
#pragma unroll
    for (int ksi = 0; ksi < 8; ksi++) {
        bf16x8 a0 = ld_bf8(ap0 + ksi * 32);
        bf16x8 a1 = ld_bf8(ap1 + ksi * 32);
        bf16x8 b0 = cvt_f8(*(const f32x8*)(wb0 + ksi * 32));
        bf16x8 b1 = cvt_f8(*(const f32x8*)(wb1 + ksi * 32));
        acc00 = MFMA16(a0, b0, acc00, 0, 0, 0);
        acc01 = MFMA16(a0, b1, acc01, 0, 0, 0);
        acc10 = MFMA16(a1, b0, acc10, 0, 0, 0);
        acc11 = MFMA16(a1, b1, acc11, 0, 0, 0);
    }
#pragma unroll
    for (int am = 0; am < 2; am++) {
#pragma unroll
        for (int r = 0; r < 4; r++) {
            const int cm = m0 + am * 16 + h4 * 4 + r;
#pragma unroll
            for (int bn = 0; bn < 2; bn++) {
                float v = am ? (bn ? acc11[r] : acc10[r]) : (bn ? acc01[r] : acc00[r]);
                out[cm * 256 + n0 + bn * 16 + cl] = v;
            }
        }
    }
}

extern "C" void kernel_launch(void* const* d_in, const int* in_sizes, int n_in,
                              void* d_out, int out_size, void* d_ws, size_t ws_size,
                              hipStream_t stream) {
    const float* query = (const float*)d_in[0];
    const float* key_ = (const float*)d_in[1];
    const float* value = (const float*)d_in[2];
    const float* radial = (const float*)d_in[3];
    const float* Wq = (const float*)d_in[4];
    const float* Wk = (const float*)d_in[5];
    const float* Wv = (const float*)d_in[6];
    const float* Wo = (const float*)d_in[7];

    unsigned short* wq = (unsigned short*)d_ws;  // Q[h][m][d]  2MB
    unsigned short* wk = wq + SEQ * 256;         // K[h][n][d]  2MB
    unsigned short* wv = wk + SEQ * 256;         // Vt[h][d][n] 2MB
    unsigned short* wa = wv + SEQ * 256;         // attn bf16   2MB

    proj_kernel<<<dim3(256, 3), 256, 0, stream>>>(query, key_, value, Wq, Wk, Wv,
                                                  radial, wq, wk, wv);
    attn_kernel<<<512, 256, 0, stream>>>(wq, wk, wv, wa);
    oproj_kernel<<<256, 256, 0, stream>>>(wa, Wo, (float*)d_out);
}

// Round 3
// 78.741 us; speedup vs baseline: 2.3216x; 1.2660x over previous
//
#include <hip/hip_runtime.h>
#include <cstdint>

#define SEQ 4096
#define NH 8
#define DH 32

typedef __bf16 bf16x8 __attribute__((ext_vector_type(8)));
typedef float f32x4 __attribute__((ext_vector_type(4)));
typedef float f32x8 __attribute__((ext_vector_type(8)));
typedef float f32x16 __attribute__((ext_vector_type(16)));
typedef unsigned short u16x8 __attribute__((ext_vector_type(8)));
typedef unsigned u32x4 __attribute__((ext_vector_type(4)));
typedef unsigned u32x2 __attribute__((ext_vector_type(2)));
typedef int i32x2 __attribute__((ext_vector_type(2)));

#define MFMA16 __builtin_amdgcn_mfma_f32_16x16x32_bf16
#define MFMA32 __builtin_amdgcn_mfma_f32_32x32x16_bf16

#define QSCALE 0.25503902427f  /* (1/sqrt(32)) * log2(e) */

__device__ inline bf16x8 ld_bf8(const unsigned short* p) {
    return __builtin_bit_cast(bf16x8, *(const u16x8*)p);
}
__device__ inline unsigned short bfbits(float v) {
    return __builtin_bit_cast(unsigned short, (__bf16)v);
}
__device__ inline bf16x8 cvt_f8(f32x8 v) {
    bf16x8 r;
#pragma unroll
    for (int i = 0; i < 8; i++) r[i] = (__bf16)v[i];
    return r;
}
__device__ inline unsigned cvtpk(float lo, float hi) {
    unsigned r;
    asm("v_cvt_pk_bf16_f32 %0, %1, %2" : "=v"(r) : "v"(lo), "v"(hi));
    return r;
}

// ---------------- Kernel 0: preconvert f32 -> bf16 ----------------
// X0 gets QSCALE folded in (q-projection is linear in X0).
__global__ __launch_bounds__(256) void precvt_kernel(
    const float* __restrict__ x0, const float* __restrict__ x1, const float* __restrict__ x2,
    const float* __restrict__ w0, const float* __restrict__ w1, const float* __restrict__ w2,
    const float* __restrict__ w3,
    unsigned short* __restrict__ bx0, unsigned short* __restrict__ bx1,
    unsigned short* __restrict__ bx2, unsigned short* __restrict__ bw0,
    unsigned short* __restrict__ bw1, unsigned short* __restrict__ bw2,
    unsigned short* __restrict__ bw3) {
    const int i = blockIdx.x * 256 + threadIdx.x;  // 425984 total chunks of 8
    const float* src;
    unsigned short* dst;
    int off;
    float scale = 1.0f;
    if (i < 393216) {  // 3 x 131072 X-chunks
        const int sel = i >> 17;
        off = i & 131071;
        src = (sel == 0) ? x0 : (sel == 1) ? x1 : x2;
        dst = (sel == 0) ? bx0 : (sel == 1) ? bx1 : bx2;
        if (sel == 0) scale = QSCALE;
    } else {  // 4 x 8192 W-chunks
        const int j = i - 393216;
        const int sel = j >> 13;
        off = j & 8191;
        src = (sel == 0) ? w0 : (sel == 1) ? w1 : (sel == 2) ? w2 : w3;
        dst = (sel == 0) ? bw0 : (sel == 1) ? bw1 : (sel == 2) ? bw2 : bw3;
    }
    f32x8 v = ((const f32x8*)src)[off];
    u16x8 r;
#pragma unroll
    for (int j = 0; j < 8; j++) r[j] = bfbits(v[j] * scale);
    ((u16x8*)dst)[off] = r;
}

// ---------------- Kernel 1: QKV projections, bf16 inputs ----------------
// sel 0: Q[h][m][d]   (QSCALE already folded into bX0)
// sel 1: K[h][n][d]
// sel 2: Vt[h][d][n] *= radial[n]
__global__ __launch_bounds__(256, 4) void proj_bf16_kernel(
    const unsigned short* __restrict__ X0, const unsigned short* __restrict__ X1,
    const unsigned short* __restrict__ X2, const unsigned short* __restrict__ W0,
    const unsigned short* __restrict__ W1, const unsigned short* __restrict__ W2,
    const float* __restrict__ radial,
    unsigned short* __restrict__ outq, unsigned short* __restrict__ outk,
    unsigned short* __restrict__ outv) {
    const int sel = blockIdx.y;
    const unsigned short* X = (sel == 0) ? X0 : (sel == 1) ? X1 : X2;
    const unsigned short* W = (sel == 0) ? W0 : (sel == 1) ? W1 : W2;
    const int lane = threadIdx.x & 63;
    const int w = threadIdx.x >> 6;
    const int cl = lane & 15;
    const int h4 = lane >> 4;
    const int t = blockIdx.x * 4 + w;  // 1024 tiles: 128 x 8
    const int m0 = (t >> 3) * 32;
    const int n0 = (t & 7) * 32;

    const unsigned short* xa0 = X + (m0 + cl) * 256 + h4 * 8;
    const unsigned short* xa1 = xa0 + 16 * 256;
    const unsigned short* wb0 = W + (n0 + cl) * 256 + h4 * 8;
    const unsigned short* wb1 = wb0 + 16 * 256;

    f32x4 acc00 = {0.f, 0.f, 0.f, 0.f}, acc01 = {0.f, 0.f, 0.f, 0.f};
    f32x4 acc10 = {0.f, 0.f, 0.f, 0.f}, acc11 = {0.f, 0.f, 0.f, 0.f};
#pragma unroll
    for (int ksi = 0; ksi < 8; ksi++) {
        bf16x8 a0 = ld_bf8(xa0 + ksi * 32);
        bf16x8 a1 = ld_bf8(xa1 + ksi * 32);
        bf16x8 b0 = ld_bf8(wb0 + ksi * 32);
        bf16x8 b1 = ld_bf8(wb1 + ksi * 32);
        acc00 = MFMA16(a0, b0, acc00, 0, 0, 0);
        acc01 = MFMA16(a0, b1, acc01, 0, 0, 0);
        acc10 = MFMA16(a1, b0, acc10, 0, 0, 0);
        acc11 = MFMA16(a1, b1, acc11, 0, 0, 0);
    }

#pragma unroll
    for (int am = 0; am < 2; am++) {
#pragma unroll
        for (int r = 0; r < 4; r++) {
            const int cm = m0 + am * 16 + h4 * 4 + r;
            float rm = (sel == 2) ? radial[cm] : 0.f;
#pragma unroll
            for (int bn = 0; bn < 2; bn++) {
                float v = am ? (bn ? acc11[r] : acc10[r]) : (bn ? acc01[r] : acc00[r]);
                const int cn = n0 + bn * 16 + cl;
                const int h = cn >> 5, d = cn & 31;
                if (sel == 0) outq[(h * SEQ + cm) * DH + d] = bfbits(v);
                else if (sel == 1) outk[(h * SEQ + cm) * DH + d] = bfbits(v);
                else outv[(h * DH + d) * SEQ + cm] = bfbits(v * rm);
            }
        }
    }
}

// ---- fallback (small ws): round-2 proj with inline f32->bf16 conversion ----
__global__ __launch_bounds__(256) void proj_f32_kernel(
    const float* __restrict__ X0, const float* __restrict__ X1, const float* __restrict__ X2,
    const float* __restrict__ W0, const float* __restrict__ W1, const float* __restrict__ W2,
    const float* __restrict__ radial,
    unsigned short* __restrict__ outq, unsigned short* __restrict__ outk,
    unsigned short* __restrict__ outv) {
    const int sel = blockIdx.y;
    const float* X = (sel == 0) ? X0 : (sel == 1) ? X1 : X2;
    const float* W = (sel == 0) ? W0 : (sel == 1) ? W1 : W2;
    const int lane = threadIdx.x & 63;
    const int w = threadIdx.x >> 6;
    const int cl = lane & 15;
    const int h4 = lane >> 4;
    const int t = blockIdx.x * 4 + w;
    const int m0 = (t >> 3) * 32;
    const int n0 = (t & 7) * 32;

    const float* xa0 = X + (m0 + cl) * 256 + h4 * 8;
    const float* xa1 = xa0 + 16 * 256;
    const float* wb0 = W + (n0 + cl) * 256 + h4 * 8;
    const float* wb1 = wb0 + 16 * 256;

    f32x4 acc00 = {0.f, 0.f, 0.f, 0.f}, acc01 = {0.f, 0.f, 0.f, 0.f};
    f32x4 acc10 = {0.f, 0.f, 0.f, 0.f}, acc11 = {0.f, 0.f, 0.f, 0.f};
#pragma unroll
    for (int ksi = 0; ksi < 8; ksi++) {
        bf16x8 a0 = cvt_f8(*(const f32x8*)(xa0 + ksi * 32));
        bf16x8 a1 = cvt_f8(*(const f32x8*)(xa1 + ksi * 32));
        bf16x8 b0 = cvt_f8(*(const f32x8*)(wb0 + ksi * 32));
        bf16x8 b1 = cvt_f8(*(const f32x8*)(wb1 + ksi * 32));
        acc00 = MFMA16(a0, b0, acc00, 0, 0, 0);
        acc01 = MFMA16(a0, b1, acc01, 0, 0, 0);
        acc10 = MFMA16(a1, b0, acc10, 0, 0, 0);
        acc11 = MFMA16(a1, b1, acc11, 0, 0, 0);
    }
#pragma unroll
    for (int am = 0; am < 2; am++) {
#pragma unroll
        for (int r = 0; r < 4; r++) {
            const int cm = m0 + am * 16 + h4 * 4 + r;
            float rm = (sel == 2) ? radial[cm] : 0.f;
#pragma unroll
            for (int bn = 0; bn < 2; bn++) {
                float v = am ? (bn ? acc11[r] : acc10[r]) : (bn ? acc01[r] : acc00[r]);
                const int cn = n0 + bn * 16 + cl;
                const int h = cn >> 5, d = cn & 31;
                if (sel == 0) outq[(h * SEQ + cm) * DH + d] = bfbits(v * QSCALE);
                else if (sel == 1) outk[(h * SEQ + cm) * DH + d] = bfbits(v);
                else outv[(h * DH + d) * SEQ + cm] = bfbits(v * rm);
            }
        }
    }
}

// ---------------- Kernel 2: flash attention, swapped operands, KSPLIT=4 ----------------
// Block = one 32-row q-tile; wave w covers keys [w*1024, (w+1)*1024).
// S^T = mfma32(K,Q): lane holds 16 scores of q-row (lane&31); lane-local softmax.
// O^T = mfma32(Vt,P). Partials combined through LDS at the end.
__global__ __launch_bounds__(256, 4) void attn_kernel(
    const unsigned short* __restrict__ Q, const unsigned short* __restrict__ K,
    const unsigned short* __restrict__ Vt, unsigned short* __restrict__ An) {
    __shared__ float cO[3][64][17];
    __shared__ float cls[3][32];
    const int lane = threadIdx.x & 63;
    const int w = threadIdx.x >> 6;  // key-quarter index
    const int l31 = lane & 31;
    const int hi = lane >> 5;

    // XCD-chunked remap: 1024 blocks head-major -> each XCD owns one head
    int bid = blockIdx.x;
    bid = (bid & 7) * 128 + (bid >> 3);
    const int head = bid >> 7;
    const int m0 = (bid & 127) * 32;

    const unsigned short* qh = Q + head * (SEQ * DH);
    const unsigned short* kh = K + head * (SEQ * DH);
    const unsigned short* vh = Vt + head * (DH * SEQ);

    const bf16x8 qf0 = ld_bf8(qh + (m0 + l31) * DH + hi * 8);       // d in [0,16)
    const bf16x8 qf1 = ld_bf8(qh + (m0 + l31) * DH + 16 + hi * 8);  // d in [16,32)

    f32x16 oacc = {0.f, 0.f, 0.f, 0.f, 0.f, 0.f, 0.f, 0.f,
                   0.f, 0.f, 0.f, 0.f, 0.f, 0.f, 0.f, 0.f};
    float ls = 0.f;

    const unsigned short* kp = kh + (w * 1024 + l31) * DH + hi * 8;
    const unsigned short* vp = vh + l31 * SEQ + w * 1024 + hi * 8;

    for (int nb = 0; nb < 32; nb++) {
        bf16x8 kf0 = ld_bf8(kp);
        bf16x8 kf1 = ld_bf8(kp + 16);
        f32x16 s = {0.f, 0.f, 0.f, 0.f, 0.f, 0.f, 0.f, 0.f,
                    0.f, 0.f, 0.f, 0.f, 0.f, 0.f, 0.f, 0.f};
        __builtin_amdgcn_s_setprio(1);
        s = MFMA32(kf0, qf0, s, 0, 0, 0);
        s = MFMA32(kf1, qf1, s, 0, 0, 0);
        __builtin_amdgcn_s_setprio(0);
        // lane holds P[q=l31][key = n0 + (reg&3)+8*(reg>>2)+4*hi]
        float p[16];
#pragma unroll
        for (int r = 0; r < 16; r++) p[r] = __builtin_amdgcn_exp2f(s[r]);
        {
            float s01 = p[0] + p[1], s23 = p[2] + p[3], s45 = p[4] + p[5], s67 = p[6] + p[7];
            float s89 = p[8] + p[9], sab = p[10] + p[11], scd = p[12] + p[13], sef = p[14] + p[15];
            ls += ((s01 + s23) + (s45 + s67)) + ((s89 + sab) + (scd + sef));
        }
        // Repack P into the B-operand fragment (col=q, k=key) for the two PV MFMAs.
        unsigned a01 = cvtpk(p[0], p[1]), a23 = cvtpk(p[2], p[3]);
        unsigned a45 = cvtpk(p[4], p[5]), a67 = cvtpk(p[6], p[7]);
        i32x2 r0 = __builtin_amdgcn_permlane32_swap((int)a01, (int)a45, false, false);
        i32x2 r1 = __builtin_amdgcn_permlane32_swap((int)a23, (int)a67, false, false);
        u32x4 pb0w = {(unsigned)r0[0], (unsigned)r1[0], (unsigned)r0[1], (unsigned)r1[1]};
        unsigned a89 = cvtpk(p[8], p[9]), aab = cvtpk(p[10], p[11]);
        unsigned acd = cvtpk(p[12], p[13]), aef = cvtpk(p[14], p[15]);
        i32x2 r2 = __builtin_amdgcn_permlane32_swap((int)a89, (int)acd, false, false);
        i32x2 r3 = __builtin_amdgcn_permlane32_swap((int)aab, (int)aef, false, false);
        u32x4 pb1w = {(unsigned)r2[0], (unsigned)r3[0], (unsigned)r2[1], (unsigned)r3[1]};

        bf16x8 vt0 = ld_bf8(vp);       // keys [n0, n0+16)
        bf16x8 vt1 = ld_bf8(vp + 16);  // keys [n0+16, n0+32)
        __builtin_amdgcn_s_setprio(1);
        oacc = MFMA32(vt0, __builtin_bit_cast(bf16x8, pb0w), oacc, 0, 0, 0);
        oacc = MFMA32(vt1, __builtin_bit_cast(bf16x8, pb1w), oacc, 0, 0, 0);
        __builtin_amdgcn_s_setprio(0);
        kp += 32 * DH;
        vp += 32;
    }

    ls += __shfl_xor(ls, 32);
    if (w > 0) {
#pragma unroll
        for (int i = 0; i < 16; i++) cO[w - 1][lane][i] = oacc[i];
        if (hi == 0) cls[w - 1][l31] = ls;
    }
    __syncthreads();
    if (w == 0) {
#pragma unroll
        for (int j = 0; j < 3; j++) {
#pragma unroll
            for (int i = 0; i < 16; i++) oacc[i] += cO[j][lane][i];
            ls += cls[j][l31];
        }
        const float inv = 1.0f / ls;
        unsigned short* op = An + (m0 + l31) * 256 + head * DH;
#pragma unroll
        for (int g = 0; g < 4; g++) {
            // regs 4g..4g+3 -> d = 8g + 4*hi + (0..3), consecutive
            unsigned lo = cvtpk(oacc[4 * g] * inv, oacc[4 * g + 1] * inv);
            unsigned hw = cvtpk(oacc[4 * g + 2] * inv, oacc[4 * g + 3] * inv);
            *(u32x2*)(op + 8 * g + 4 * hi) = (u32x2){lo, hw};
        }
    }
}

// ---------------- Kernel 3: output projection, bf16 Wo (32x16 tile / wave) ----------------
__global__ __launch_bounds__(256, 4) void oproj_bf16_kernel(
    const unsigned short* __restrict__ An, const unsigned short* __restrict__ Wo,
    float* __restrict__ out) {
    const int lane = threadIdx.x & 63;
    const int w = threadIdx.x >> 6;
    const int cl = lane & 15;
    const int h4 = lane >> 4;
    const int t = blockIdx.x * 4 + w;  // 2048 tiles: 128 m x 16 n
    const int m0 = (t >> 4) * 32;
    const int n0 = (t & 15) * 16;

    const unsigned short* ap0 = An + (m0 + cl) * 256 + h4 * 8;
    const unsigned short* ap1 = ap0 + 16 * 256;
    const unsigned short* wb0 = Wo + (n0 + cl) * 256 + h4 * 8;

    f32x4 acc00 = {0.f, 0.f, 0.f, 0.f}, acc10 = {0.f, 0.f, 0.f, 0.f};
#pragma unroll
    for (int ksi = 0; ksi < 8; ksi++) {
        bf16x8 a0 = ld_bf8(ap0 + ksi * 32);
        bf16x8 a1 = ld_bf8(ap1 + ksi * 32);
        bf16x8 b0 = ld_bf8(wb0 + ksi * 32);
        acc00 = MFMA16(a0, b0, acc00, 0, 0, 0);
        acc10 = MFMA16(a1, b0, acc10, 0, 0, 0);
    }
#pragma unroll
    for (int am = 0; am < 2; am++) {
#pragma unroll
        for (int r = 0; r < 4; r++) {
            const int cm = m0 + am * 16 + h4 * 4 + r;
            out[cm * 256 + n0 + cl] = am ? acc10[r] : acc00[r];
        }
    }
}

// ---- fallback oproj (f32 Wo, inline cvt) ----
__global__ __launch_bounds__(256) void oproj_f32_kernel(
    const unsigned short* __restrict__ An, const float* __restrict__ Wo,
    float* __restrict__ out) {
    const int lane = threadIdx.x & 63;
    const int w = threadIdx.x >> 6;
    const int cl = lane & 15;
    const int h4 = lane >> 4;
    const int t = blockIdx.x * 4 + w;
    const int m0 = (t >> 3) * 32;
    const int n0 = (t & 7) * 32;

    const unsigned short* ap0 = An + (m0 + cl) * 256 + h4 * 8;
    const unsigned short* ap1 = ap0 + 16 * 256;
    const float* wb0 = Wo + (n0 + cl) * 256 + h4 * 8;
    const float* wb1 = wb0 + 16 * 256;

    f32x4 acc00 = {0.f, 0.f, 0.f, 0.f}, acc01 = {0.f, 0.f, 0.f, 0.f};
    f32x4 acc10 = {0.f, 0.f, 0.f, 0.f}, acc11 = {0.f, 0.f, 0.f, 0.f};
#pragma unroll
    for (int ksi = 0; ksi < 8; ksi++) {
        bf16x8 a0 = ld_bf8(ap0 + ksi * 32);
        bf16x8 a1 = ld_bf8(ap1 + ksi * 32);
        bf16x8 b0 = cvt_f8(*(const f32x8*)(wb0 + ksi * 32));
        bf16x8 b1 = cvt_f8(*(const f32x8*)(wb1 + ksi * 32));
        acc00 = MFMA16(a0, b0, acc00, 0, 0, 0);
        acc01 = MFMA16(a0, b1, acc01, 0, 0, 0);
        acc10 = MFMA16(a1, b0, acc10, 0, 0, 0);
        acc11 = MFMA16(a1, b1, acc11, 0, 0, 0);
    }
#pragma unroll
    for (int am = 0; am < 2; am++) {
#pragma unroll
        for (int r = 0; r < 4; r++) {
            const int cm = m0 + am * 16 + h4 * 4 + r;
#pragma unroll
            for (int bn = 0; bn < 2; bn++) {
                float v = am ? (bn ? acc11[r] : acc10[r]) : (bn ? acc01[r] : acc00[r]);
                out[cm * 256 + n0 + bn * 16 + cl] = v;
            }
        }
    }
}

extern "C" void kernel_launch(void* const* d_in, const int* in_sizes, int n_in,
                              void* d_out, int out_size, void* d_ws, size_t ws_size,
                              hipStream_t stream) {
    const float* query = (const float*)d_in[0];
    const float* key_ = (const float*)d_in[1];
    const float* value = (const float*)d_in[2];
    const float* radial = (const float*)d_in[3];
    const float* Wq = (const float*)d_in[4];
    const float* Wk = (const float*)d_in[5];
    const float* Wv = (const float*)d_in[6];
    const float* Wo = (const float*)d_in[7];

    const size_t MB = 1u << 20;
    uint8_t* base = (uint8_t*)d_ws;
    unsigned short* wq = (unsigned short*)(base + 0 * MB);   // Q[h][m][d]  2MB
    unsigned short* wk = (unsigned short*)(base + 2 * MB);   // K[h][n][d]  2MB
    unsigned short* wv = (unsigned short*)(base + 4 * MB);   // Vt[h][d][n] 2MB
    unsigned short* wa = (unsigned short*)(base + 6 * MB);   // attn bf16   2MB

    const bool big = ws_size >= (size_t)(15.5 * 1024 * 1024);
    if (big) {
        unsigned short* bX0 = (unsigned short*)(base + 8 * MB);
        unsigned short* bX1 = (unsigned short*)(base + 10 * MB);
        unsigned short* bX2 = (unsigned short*)(base + 12 * MB);
        unsigned short* bWq = (unsigned short*)(base + 14 * MB);
        unsigned short* bWk = (unsigned short*)(base + 14 * MB + 128 * 1024);
        unsigned short* bWv = (unsigned short*)(base + 14 * MB + 256 * 1024);
        unsigned short* bWo = (unsigned short*)(base + 14 * MB + 384 * 1024);
        precvt_kernel<<<1664, 256, 0, stream>>>(query, key_, value, Wq, Wk, Wv, Wo,
                                                bX0, bX1, bX2, bWq, bWk, bWv, bWo);
        proj_bf16_kernel<<<dim3(256, 3), 256, 0, stream>>>(bX0, bX1, bX2, bWq, bWk, bWv,
                                                           radial, wq, wk, wv);
        attn_kernel<<<1024, 256, 0, stream>>>(wq, wk, wv, wa);
        oproj_bf16_kernel<<<512, 256, 0, stream>>>(wa, bWo, (float*)d_out);
    } else {
        proj_f32_kernel<<<dim3(256, 3), 256, 0, stream>>>(query, key_, value, Wq, Wk, Wv,
                                                          radial, wq, wk, wv);
        attn_kernel<<<1024, 256, 0, stream>>>(wq, wk, wv, wa);
        oproj_f32_kernel<<<256, 256, 0, stream>>>(wa, Wo, (float*)d_out);
    }
}